// Round 20
// baseline (48.927 us; speedup 1.0000x reference)
//
#include <hip/hip_runtime.h>
#include <hip/hip_bf16.h>

#define K_SEL 16
#define NCAND 20
#define NCMAX 24   // selection may include a whole 24-bit-score tie class

typedef __attribute__((ext_vector_type(8))) short short8;
typedef __attribute__((ext_vector_type(4))) short short4v;
typedef __attribute__((ext_vector_type(4))) float f32x4;

__device__ __forceinline__ short f2bf_bits(float v) {
    union { __hip_bfloat16 b; short s; } u;
    u.b = __float2bfloat16(v);                    // RNE HW convert
    return u.s;
}
__device__ __forceinline__ float bf2f_bits(short h) {
    return __uint_as_float(((unsigned)(unsigned short)h) << 16);
}
__device__ __forceinline__ float readlane_f(float v, int l) {
    return __int_as_float(__builtin_amdgcn_readlane(__float_as_int(v), l));
}

// ---------------------------------------------------------------------------
// pack body (tail blocks of simtopk): weights -> split-bf16 hi/lo planes,
// B-fragment order idx = ((ks*N + n)*4 + kb)*8 + i <-> W[ks*32+kb*8+i][n].
// ---------------------------------------------------------------------------
__device__ __noinline__ void pack_body(
    int t,
    const float* __restrict__ s0w, const float* __restrict__ s1w,
    const float* __restrict__ sow, const float* __restrict__ o0w,
    const float* __restrict__ o1w, const float* __restrict__ oow,
    short* __restrict__ wpack)
{
    if (t >= 69632) return;
    int l, base;
    if      (t <  8192) { l = 0; base = 0;     }
    else if (t < 24576) { l = 1; base = 8192;  }
    else if (t < 32768) { l = 2; base = 24576; }
    else if (t < 45056) { l = 3; base = 32768; }
    else if (t < 61440) { l = 4; base = 45056; }
    else                { l = 5; base = 61440; }

    const float* W = (l == 0) ? s0w : (l == 1) ? s1w : (l == 2) ? sow
                   : (l == 3) ? o0w : (l == 4) ? o1w : oow;
    int N    = (l == 2 || l == 5) ? 64 : 128;
    int Kr   = (l == 0) ? 48 : (l == 3) ? 96 : 128;
    int woff = (l == 0) ? 0 : (l == 1) ? 16384 : (l == 2) ? 49152
             : (l == 3) ? 65536 : (l == 4) ? 90112 : 122880;
    int sz   = (l == 2 || l == 5) ? 8192 : (l == 3) ? 12288 : (l == 0) ? 8192 : 16384;

    int e = t - base;
    int i = e & 7, kb = (e >> 3) & 3, rem = e >> 5;
    int n = rem % N, ks = rem / N;
    int k = ks * 32 + kb * 8 + i;
    float v = (k < Kr) ? W[k * N + n] : 0.0f;
    short hi = f2bf_bits(v);
    float lo = v - bf2f_bits(hi);
    wpack[woff + e]      = hi;
    wpack[woff + sz + e] = f2bf_bits(lo);
}

// ---------------------------------------------------------------------------
// Kernel A v9 (R19 + SALU-lean select): 2 px/wave distances, all-thread
// staging.  Radix-select runs 23 iterations on the 24-bit SCORE PREFIX
// (bit31 always 0; index bits deferred) -> ~25% fewer SALU ops in the
// CU-serialized scalar pipe (R19 analysis: ~640 SALU/wave x 32 waves on ONE
// scalar unit/CU was ~8-9us).  Selection takes the whole prefix-tie class
// (M in [20,24], superset of exact top-20 -> superset of true top-16; fp64
// re-rank unchanged => bit-identical output).  Rare M>24: exact 8-bit
// index-radix fallback (wave-uniform branch).
// ---------------------------------------------------------------------------
template<int COMP>
__device__ __forceinline__ void simtopk_body(
    const float* __restrict__ x, float* __restrict__ feat,
    float* xsT, int* candj, double* rs, int win, int grp, int tid)
{
    const int lane = tid & 63;
    const int wv   = tid >> 6;

    // ---- stage transposed window: ALL threads; 2 f4 loads + 4 b64 writes ----
    {
        const int half = tid >> 9;                 // 0: quadrants 0,1; 1: 2,3
        const int t2   = tid & 511;
        const int c4   = t2 & 7, jb = t2 >> 3;     // jb in [0,64)
        const float4* gx = reinterpret_cast<const float4*>(x + (size_t)win * 8192);
        float4 va = gx[jb * 8 + c4 + (half ? 1024 : 0)];
        float4 vb = gx[jb * 8 + c4 + (half ? 1536 : 512)];
        const int gsw = jb ^ c4;
        char* bp = (char*)xsT + (size_t)half * 8;
        #pragma unroll
        for (int k = 0; k < 4; ++k) {
            float2 h2 = make_float2((&va.x)[k], (&vb.x)[k]);
            *(float2*)(bp + ((4 * c4 + k) * 64 + gsw) * 16) = h2;
        }
    }
    __syncthreads();

    const int plbase = (grp & 1) * 32 + wv * 2;

    const f32x4* xsT4c = reinterpret_cast<const f32x4*>(xsT);
    float acc0[4] = {0.f, 0.f, 0.f, 0.f};
    float acc1[4] = {0.f, 0.f, 0.f, 0.f};
    #pragma unroll
    for (int c = 0; c < 32; ++c) {
        f32x4 a = xsT4c[c * 64 + (lane ^ ((c >> 2) & 7))];
        float xi0 = readlane_f(a[COMP], plbase);
        float xi1 = readlane_f(a[COMP], plbase + 1);
        #pragma unroll
        for (int q = 0; q < 4; ++q) {
            acc0[q] += fabsf(a[q] - xi0);
            acc1[q] += fabsf(a[q] - xi1);
        }
    }
    unsigned int p0[4], p1[4], q0[4], q1[4];
    #pragma unroll
    for (int q = 0; q < 4; ++q) {
        p0[q] = (__float_as_uint(acc0[q]) & 0xFFFFFF00u) | (unsigned)(q * 64 + lane);
        p1[q] = (__float_as_uint(acc1[q]) & 0xFFFFFF00u) | (unsigned)(q * 64 + lane);
        q0[q] = p0[q] >> 8;
        q1[q] = p1[q] >> 8;
    }

    // ---- radix-select on 23 score-prefix bits (bit23 of q == old bit31 == 0) ----
    unsigned int T0 = 0, T1 = 0;
    #pragma unroll 1
    for (int bit = 22; bit >= 0; --bit) {
        unsigned int c0 = T0 | (1u << bit), c1 = T1 | (1u << bit);
        int n0 = __popcll(__ballot(q0[0] < c0)) + __popcll(__ballot(q0[1] < c0))
               + __popcll(__ballot(q0[2] < c0)) + __popcll(__ballot(q0[3] < c0));
        int n1 = __popcll(__ballot(q1[0] < c1)) + __popcll(__ballot(q1[1] < c1))
               + __popcll(__ballot(q1[2] < c1)) + __popcll(__ballot(q1[3] < c1));
        if (n0 < NCAND) T0 = c0;
        if (n1 < NCAND) T1 = c1;
    }
    // selection size (whole tie class): M in [NCAND, ...]
    int M0 = __popcll(__ballot(q0[0] <= T0)) + __popcll(__ballot(q0[1] <= T0))
           + __popcll(__ballot(q0[2] <= T0)) + __popcll(__ballot(q0[3] <= T0));
    int M1 = __popcll(__ballot(q1[0] <= T1)) + __popcll(__ballot(q1[1] <= T1))
           + __popcll(__ballot(q1[2] <= T1)) + __popcll(__ballot(q1[3] <= T1));

    // rare exact fallback on index bits (wave-uniform branches)
    bool fb0 = (M0 > NCMAX), fb1 = (M1 > NCMAX);
    unsigned int F0 = 0, F1 = 0;
    if (fb0) {
        unsigned int T = T0 << 8;
        #pragma unroll 1
        for (int bit = 7; bit >= 0; --bit) {
            unsigned int cand = T | (1u << bit);
            int n = __popcll(__ballot(p0[0] < cand)) + __popcll(__ballot(p0[1] < cand))
                  + __popcll(__ballot(p0[2] < cand)) + __popcll(__ballot(p0[3] < cand));
            if (n < NCAND) T = cand;
        }
        F0 = T; M0 = NCAND;
    }
    if (fb1) {
        unsigned int T = T1 << 8;
        #pragma unroll 1
        for (int bit = 7; bit >= 0; --bit) {
            unsigned int cand = T | (1u << bit);
            int n = __popcll(__ballot(p1[0] < cand)) + __popcll(__ballot(p1[1] < cand))
                  + __popcll(__ballot(p1[2] < cand)) + __popcll(__ballot(p1[3] < cand));
            if (n < NCAND) T = cand;
        }
        F1 = T; M1 = NCAND;
    }

    // ---- compact the selected sets (M0/M1 <= NCMAX) into per-wave LDS ----
    const unsigned long long lt = (1ull << lane) - 1ull;
    int base0 = 0, base1 = 0;
    #pragma unroll
    for (int q = 0; q < 4; ++q) {
        bool s0 = fb0 ? (p0[q] <= F0) : (q0[q] <= T0);
        unsigned long long m0 = __ballot(s0);
        if (s0) candj[(wv * 2 + 0) * NCMAX + base0 + __popcll(m0 & lt)] = q * 64 + lane;
        base0 += __popcll(m0);
        bool s1 = fb1 ? (p1[q] <= F1) : (q1[q] <= T1);
        unsigned long long m1 = __ballot(s1);
        if (s1) candj[(wv * 2 + 1) * NCMAX + base1 + __popcll(m1 & lt)] = q * 64 + lane;
        base1 += __popcll(m1);
    }
    asm volatile("s_waitcnt lgkmcnt(0)" ::: "memory");

    // ---- fp64 re-rank from GLOBAL rows (order unchanged -> bit-identical) ----
    const int t  = lane >> 5;
    const int cl = lane & 31;
    const int Mm = t ? M1 : M0;
    double s = 0.0;
    int myj = -1;
    if (cl < Mm) {
        myj = candj[(wv * 2 + t) * NCMAX + cl];
        const int pwin = COMP * 64 + plbase + t;          // FULL window-pixel idx
        const float4* xj = reinterpret_cast<const float4*>(x + (size_t)win * 8192 + (size_t)myj * 32);
        const float4* xp = reinterpret_cast<const float4*>(x + (size_t)win * 8192 + (size_t)pwin * 32);
        #pragma unroll
        for (int c4 = 0; c4 < 8; ++c4) {
            float4 b = xj[c4];
            float4 a = xp[c4];
            s += fabs((double)a.x - (double)b.x);
            s += fabs((double)a.y - (double)b.y);
            s += fabs((double)a.z - (double)b.z);
            s += fabs((double)a.w - (double)b.w);
        }
        rs[(wv * 2 + t) * NCMAX + cl] = s;
    }
    asm volatile("s_waitcnt lgkmcnt(0)" ::: "memory");

    if (myj >= 0) {
        int rank = 0;
        #pragma unroll 1
        for (int o = 0; o < NCMAX; ++o) {
            if (o < Mm) {
                double so = rs[(wv * 2 + t) * NCMAX + o];
                int    jo = candj[(wv * 2 + t) * NCMAX + o];
                rank += (so < s || (so == s && jo < myj)) ? 1 : 0;
            }
        }
        if (rank < K_SEL) {
            const int pwin = COMP * 64 + plbase + t;
            const int gp   = win * 256 + pwin;
            feat[gp * 48 + rank] = (float)(1.0 - s * 0.03125);
            float dh = (float)((pwin >> 4) - (myj >> 4)) * (1.0f / 15.0f);
            float dw = (float)((pwin & 15) - (myj & 15)) * (1.0f / 15.0f);
            reinterpret_cast<float2*>(feat)[gp * 24 + 8 + rank] = make_float2(dh, dw);
        }
    }
}

__global__ __launch_bounds__(1024) void simtopk_kernel(
    const float* __restrict__ x,    // (64, 256, 32) fp32
    float* __restrict__ feat,       // (16384, 48)
    const float* __restrict__ s0w, const float* __restrict__ s1w,
    const float* __restrict__ sow, const float* __restrict__ o0w,
    const float* __restrict__ o1w, const float* __restrict__ oow,
    short* __restrict__ wpack)
{
    __shared__ __align__(16) float xsT[8192];          // 32 KB
    __shared__ int    candj[16 * 2 * NCMAX];
    __shared__ double rs[16 * 2 * NCMAX];

    const int tid = threadIdx.x;

    if (blockIdx.x >= 512) {                            // pack tail blocks
        pack_body((blockIdx.x - 512) * 1024 + tid,
                  s0w, s1w, sow, o0w, o1w, oow, wpack);
        return;
    }

    const int win = blockIdx.x >> 3;
    const int grp = blockIdx.x & 7;

    switch (grp >> 1) {                                 // comp is compile-time
        case 0: simtopk_body<0>(x, feat, xsT, candj, rs, win, grp, tid); break;
        case 1: simtopk_body<1>(x, feat, xsT, candj, rs, win, grp, tid); break;
        case 2: simtopk_body<2>(x, feat, xsT, candj, rs, win, grp, tid); break;
        default: simtopk_body<3>(x, feat, xsT, candj, rs, win, grp, tid); break;
    }
}

// ---------------------------------------------------------------------------
// Kernel B (R14-proven, unchanged): 64 px/block, grid 256, 8 waves; wave owns
// one n-tile x M_rep=4 (2 for N=64) M-tiles -> weight set read once per block.
// ---------------------------------------------------------------------------
template<int K_STEPS, int N, bool RELU, bool TO_GLOBAL>
__device__ __forceinline__ void bf16_layer64(
    const short* hiIn, const short* loIn, short* hiOut, short* loOut,
    float* gout, int pbase, const short* __restrict__ wpack, int woff, int sz,
    const float* __restrict__ bias, int wv, int lane, int out_col_off)
{
    const int nt   = (N == 128) ? wv : (wv & 3);
    const int mt0  = (N == 128) ? 0  : ((wv >> 2) * 2);
    const int MREP = (N == 128) ? 4  : 2;
    const int kb   = lane >> 4;
    const int n    = nt * 16 + (lane & 15);

    f32x4 acc[4];
    #pragma unroll
    for (int m = 0; m < 4; ++m) acc[m] = (f32x4){0.f, 0.f, 0.f, 0.f};

    #pragma unroll
    for (int ks = 0; ks < K_STEPS; ++ks) {
        const int wi = woff + ((ks * N + n) * 4 + kb) * 8;
        short8 whi = *(const short8*)(wpack + wi);
        short8 wlo = *(const short8*)(wpack + wi + sz);
        const int g = ks * 4 + kb;
        #pragma unroll
        for (int m = 0; m < MREP; ++m) {
            const int m_a = (mt0 + m) * 16 + (lane & 15);
            const int off = m_a * 256 + ((g ^ (m_a & 7)) << 4);
            short8 ahi = *(const short8*)((const char*)hiIn + off);
            short8 alo = *(const short8*)((const char*)loIn + off);
            acc[m] = __builtin_amdgcn_mfma_f32_16x16x32_bf16(ahi, whi, acc[m], 0, 0, 0);
            acc[m] = __builtin_amdgcn_mfma_f32_16x16x32_bf16(ahi, wlo, acc[m], 0, 0, 0);
            acc[m] = __builtin_amdgcn_mfma_f32_16x16x32_bf16(alo, whi, acc[m], 0, 0, 0);
        }
    }

    const float bv = bias[n];
    #pragma unroll
    for (int m = 0; m < MREP; ++m) {
        #pragma unroll
        for (int r = 0; r < 4; ++r) {
            float v = acc[m][r] + bv;
            if (RELU) v = fmaxf(v, 0.0f);
            const int pw = (mt0 + m) * 16 + (lane >> 4) * 4 + r;
            if (TO_GLOBAL) {
                gout[(size_t)(pbase + pw) * 64 + n] = v;
            } else {
                const int w   = out_col_off + n;
                const int off = pw * 256 + ((((w >> 3) ^ (pw & 7))) << 4) + (w & 7) * 2;
                short h = f2bf_bits(v);
                short l = f2bf_bits(v - bf2f_bits(h));
                *(short*)((char*)hiOut + off) = h;
                *(short*)((char*)loOut + off) = l;
            }
        }
    }
}

__global__ __launch_bounds__(512) void ffn_kernel(
    const float* __restrict__ x,     // (16384, 32)
    const float* __restrict__ feat,  // (16384, 48)
    const short* __restrict__ wpack,
    const float* __restrict__ s0b, const float* __restrict__ s1b,
    const float* __restrict__ sob, const float* __restrict__ o0b,
    const float* __restrict__ o1b, const float* __restrict__ oob,
    float* __restrict__ out)         // (16384, 64)
{
    __shared__ __align__(16) short hiA[64 * 128];   // 16 KB each
    __shared__ __align__(16) short loA[64 * 128];
    __shared__ __align__(16) short hiB[64 * 128];
    __shared__ __align__(16) short loB[64 * 128];

    const int tid   = threadIdx.x;
    const int lane  = tid & 63;
    const int wv    = tid >> 6;                   // 0..7
    const int pbase = blockIdx.x * 64;

    // ---- stage feat (cols 0..47, split) + zero cols 48..63 into planes A ----
    #pragma unroll
    for (int rr = 0; rr < 2; ++rr) {
        int u = tid + rr * 512;
        if (u < 768) {
            int p = u / 12, c4 = u - p * 12;
            f32x4 v = ((const f32x4*)feat)[(size_t)(pbase + p) * 12 + c4];
            short4v h4, l4;
            #pragma unroll
            for (int j = 0; j < 4; ++j) {
                short h = f2bf_bits(v[j]);
                h4[j] = h;
                l4[j] = f2bf_bits(v[j] - bf2f_bits(h));
            }
            int off = p * 256 + ((((c4 >> 1) ^ (p & 7))) << 4) + (c4 & 1) * 8;
            *(short4v*)((char*)hiA + off) = h4;
            *(short4v*)((char*)loA + off) = l4;
        }
    }
    if (tid < 256) {
        int p = tid >> 2, sel = tid & 3;          // 64 rows x {g6,g7} x {hi,lo}
        int g = 6 + (sel & 1);
        int off = p * 256 + ((g ^ (p & 7)) << 4);
        short8 z = (short8){0,0,0,0,0,0,0,0};
        if (sel >> 1) *(short8*)((char*)loA + off) = z;
        else          *(short8*)((char*)hiA + off) = z;
    }
    __syncthreads();

    // L1: 48(+pad) -> 128 relu   (A -> B)
    bf16_layer64<2, 128, true, false>(hiA, loA, hiB, loB, nullptr, pbase,
                                      wpack, 0, 8192, s0b, wv, lane, 0);
    __syncthreads();
    // L2: 128 -> 128 relu  (B -> A)
    bf16_layer64<4, 128, true, false>(hiB, loB, hiA, loA, nullptr, pbase,
                                      wpack, 16384, 16384, s1b, wv, lane, 0);
    __syncthreads();
    // L3: 128 -> 64 (sf) into B cols 32..95 ; stage x into B cols 0..31
    {
        int p = tid >> 3, c4 = tid & 7;           // 512 threads = 64 rows x 8
        f32x4 v = ((const f32x4*)x)[(size_t)(pbase + p) * 8 + c4];
        short4v h4, l4;
        #pragma unroll
        for (int j = 0; j < 4; ++j) {
            short h = f2bf_bits(v[j]);
            h4[j] = h;
            l4[j] = f2bf_bits(v[j] - bf2f_bits(h));
        }
        int off = p * 256 + ((((c4 >> 1) ^ (p & 7))) << 4) + (c4 & 1) * 8;
        *(short4v*)((char*)hiB + off) = h4;
        *(short4v*)((char*)loB + off) = l4;
    }
    bf16_layer64<4, 64, false, false>(hiA, loA, hiB, loB, nullptr, pbase,
                                      wpack, 49152, 8192, sob, wv, lane, 32);
    __syncthreads();
    // L4: 96 -> 128 relu  (B -> A)
    bf16_layer64<3, 128, true, false>(hiB, loB, hiA, loA, nullptr, pbase,
                                      wpack, 65536, 12288, o0b, wv, lane, 0);
    __syncthreads();
    // L5: 128 -> 128 relu  (A -> B)
    bf16_layer64<4, 128, true, false>(hiA, loA, hiB, loB, nullptr, pbase,
                                      wpack, 90112, 16384, o1b, wv, lane, 0);
    __syncthreads();
    // L6: 128 -> 64 (+bias) -> out
    bf16_layer64<4, 64, false, true>(hiB, loB, nullptr, nullptr, out, pbase,
                                     wpack, 122880, 8192, oob, wv, lane, 0);
}

extern "C" void kernel_launch(void* const* d_in, const int* in_sizes, int n_in,
                              void* d_out, int out_size, void* d_ws, size_t ws_size,
                              hipStream_t stream) {
    const float* x    = (const float*)d_in[0];
    const float* s0w  = (const float*)d_in[1];
    const float* s0b  = (const float*)d_in[2];
    const float* s1w  = (const float*)d_in[3];
    const float* s1b  = (const float*)d_in[4];
    const float* sow  = (const float*)d_in[5];
    const float* sob  = (const float*)d_in[6];
    const float* o0w  = (const float*)d_in[7];
    const float* o0b  = (const float*)d_in[8];
    const float* o1w  = (const float*)d_in[9];
    const float* o1b  = (const float*)d_in[10];
    const float* oow  = (const float*)d_in[11];
    const float* oob  = (const float*)d_in[12];

    short* wpack = (short*)d_ws;                      // 278528 B
    float* feat  = (float*)((char*)d_ws + 524288);    // 16384*48 fp32
    float* out   = (float*)d_out;

    simtopk_kernel<<<580, 1024, 0, stream>>>(x, feat,
                                             s0w, s1w, sow, o0w, o1w, oow, wpack);
    ffn_kernel<<<256, 512, 0, stream>>>(x, feat, wpack,
                                        s0b, s1b, sob, o0b, o1b, oob,
                                        out);
}

// Round 21
// 47.414 us; speedup vs baseline: 1.0319x; 1.0319x over previous
//
#include <hip/hip_runtime.h>
#include <hip/hip_bf16.h>

#define K_SEL 16
#define NCAND 20

typedef __attribute__((ext_vector_type(8))) short short8;
typedef __attribute__((ext_vector_type(4))) short short4v;
typedef __attribute__((ext_vector_type(4))) float f32x4;

__device__ __forceinline__ short f2bf_bits(float v) {
    union { __hip_bfloat16 b; short s; } u;
    u.b = __float2bfloat16(v);                    // RNE HW convert
    return u.s;
}
__device__ __forceinline__ float bf2f_bits(short h) {
    return __uint_as_float(((unsigned)(unsigned short)h) << 16);
}
__device__ __forceinline__ float readlane_f(float v, int l) {
    return __int_as_float(__builtin_amdgcn_readlane(__float_as_int(v), l));
}

// ---------------------------------------------------------------------------
// pack body (tail blocks of simtopk): weights -> split-bf16 hi/lo planes,
// B-fragment order idx = ((ks*N + n)*4 + kb)*8 + i <-> W[ks*32+kb*8+i][n].
// __noinline__ so the hot simtopk path's regalloc is not perturbed (R9 lesson).
// ---------------------------------------------------------------------------
__device__ __noinline__ void pack_body(
    int t,
    const float* __restrict__ s0w, const float* __restrict__ s1w,
    const float* __restrict__ sow, const float* __restrict__ o0w,
    const float* __restrict__ o1w, const float* __restrict__ oow,
    short* __restrict__ wpack)
{
    if (t >= 69632) return;
    int l, base;
    if      (t <  8192) { l = 0; base = 0;     }
    else if (t < 24576) { l = 1; base = 8192;  }
    else if (t < 32768) { l = 2; base = 24576; }
    else if (t < 45056) { l = 3; base = 32768; }
    else if (t < 61440) { l = 4; base = 45056; }
    else                { l = 5; base = 61440; }

    const float* W = (l == 0) ? s0w : (l == 1) ? s1w : (l == 2) ? sow
                   : (l == 3) ? o0w : (l == 4) ? o1w : oow;
    int N    = (l == 2 || l == 5) ? 64 : 128;
    int Kr   = (l == 0) ? 48 : (l == 3) ? 96 : 128;
    int woff = (l == 0) ? 0 : (l == 1) ? 16384 : (l == 2) ? 49152
             : (l == 3) ? 65536 : (l == 4) ? 90112 : 122880;
    int sz   = (l == 2 || l == 5) ? 8192 : (l == 3) ? 12288 : (l == 0) ? 8192 : 16384;

    int e = t - base;
    int i = e & 7, kb = (e >> 3) & 3, rem = e >> 5;
    int n = rem % N, ks = rem / N;
    int k = ks * 32 + kb * 8 + i;
    float v = (k < Kr) ? W[k * N + n] : 0.0f;
    short hi = f2bf_bits(v);
    float lo = v - bf2f_bits(hi);
    wpack[woff + e]      = hi;
    wpack[woff + sz + e] = f2bf_bits(lo);
}

// ---------------------------------------------------------------------------
// Kernel A (R19-measured-best, byte-exact): 2 px/wave distances (readlane of
// the candidate vector), all-thread staging (each thread: 2 f4 loads + 4 b64
// writes -> bit-identical LDS image, no idle waves), radix top-20, fp64
// re-rank from global rows, rank via LDS rs[].
// grid 512(+68 pack tail) = 64 win x 8 groups of 32 px; block 1024 = 16 waves.
// ---------------------------------------------------------------------------
template<int COMP>
__device__ __forceinline__ void simtopk_body(
    const float* __restrict__ x, float* __restrict__ feat,
    float* xsT, int* candj, double* rs, int win, int grp, int tid)
{
    const int lane = tid & 63;
    const int wv   = tid >> 6;

    // ---- stage transposed window: ALL threads; 2 f4 loads + 4 b64 writes ----
    {
        const int half = tid >> 9;                 // 0: quadrants 0,1; 1: 2,3
        const int t2   = tid & 511;
        const int c4   = t2 & 7, jb = t2 >> 3;     // jb in [0,64)
        const float4* gx = reinterpret_cast<const float4*>(x + (size_t)win * 8192);
        float4 va = gx[jb * 8 + c4 + (half ? 1024 : 0)];
        float4 vb = gx[jb * 8 + c4 + (half ? 1536 : 512)];
        const int gsw = jb ^ c4;
        char* bp = (char*)xsT + (size_t)half * 8;
        #pragma unroll
        for (int k = 0; k < 4; ++k) {
            float2 h2 = make_float2((&va.x)[k], (&vb.x)[k]);
            *(float2*)(bp + ((4 * c4 + k) * 64 + gsw) * 16) = h2;
        }
    }
    __syncthreads();

    const int plbase = (grp & 1) * 32 + wv * 2;

    const f32x4* xsT4c = reinterpret_cast<const f32x4*>(xsT);
    float acc0[4] = {0.f, 0.f, 0.f, 0.f};
    float acc1[4] = {0.f, 0.f, 0.f, 0.f};
    #pragma unroll
    for (int c = 0; c < 32; ++c) {
        f32x4 a = xsT4c[c * 64 + (lane ^ ((c >> 2) & 7))];
        float xi0 = readlane_f(a[COMP], plbase);
        float xi1 = readlane_f(a[COMP], plbase + 1);
        #pragma unroll
        for (int q = 0; q < 4; ++q) {
            acc0[q] += fabsf(a[q] - xi0);
            acc1[q] += fabsf(a[q] - xi1);
        }
    }
    unsigned int p0[4], p1[4];
    #pragma unroll
    for (int q = 0; q < 4; ++q) {
        p0[q] = (__float_as_uint(acc0[q]) & 0xFFFFFF00u) | (unsigned)(q * 64 + lane);
        p1[q] = (__float_as_uint(acc1[q]) & 0xFFFFFF00u) | (unsigned)(q * 64 + lane);
    }

    unsigned int T0 = 0, T1 = 0;
    for (int bit = 31; bit >= 0; --bit) {
        unsigned int c0 = T0 | (1u << bit), c1 = T1 | (1u << bit);
        int n0 = __popcll(__ballot(p0[0] < c0)) + __popcll(__ballot(p0[1] < c0))
               + __popcll(__ballot(p0[2] < c0)) + __popcll(__ballot(p0[3] < c0));
        int n1 = __popcll(__ballot(p1[0] < c1)) + __popcll(__ballot(p1[1] < c1))
               + __popcll(__ballot(p1[2] < c1)) + __popcll(__ballot(p1[3] < c1));
        if (n0 < NCAND) T0 = c0;
        if (n1 < NCAND) T1 = c1;
    }

    const unsigned long long lt = (1ull << lane) - 1ull;
    int base0 = 0, base1 = 0;
    #pragma unroll
    for (int q = 0; q < 4; ++q) {
        bool s0 = (p0[q] <= T0);
        unsigned long long m0 = __ballot(s0);
        if (s0) candj[(wv * 2 + 0) * NCAND + base0 + __popcll(m0 & lt)] = q * 64 + lane;
        base0 += __popcll(m0);
        bool s1 = (p1[q] <= T1);
        unsigned long long m1 = __ballot(s1);
        if (s1) candj[(wv * 2 + 1) * NCAND + base1 + __popcll(m1 & lt)] = q * 64 + lane;
        base1 += __popcll(m1);
    }
    asm volatile("s_waitcnt lgkmcnt(0)" ::: "memory");

    const int t  = lane >> 5;
    const int cl = lane & 31;
    double s = 0.0;
    int myj = -1;
    if (cl < NCAND) {
        myj = candj[(wv * 2 + t) * NCAND + cl];
        const int pwin = COMP * 64 + plbase + t;          // FULL window-pixel idx
        const float4* xj = reinterpret_cast<const float4*>(x + (size_t)win * 8192 + (size_t)myj * 32);
        const float4* xp = reinterpret_cast<const float4*>(x + (size_t)win * 8192 + (size_t)pwin * 32);
        #pragma unroll
        for (int c4 = 0; c4 < 8; ++c4) {
            float4 b = xj[c4];
            float4 a = xp[c4];
            s += fabs((double)a.x - (double)b.x);
            s += fabs((double)a.y - (double)b.y);
            s += fabs((double)a.z - (double)b.z);
            s += fabs((double)a.w - (double)b.w);
        }
        rs[(wv * 2 + t) * NCAND + cl] = s;
    }
    asm volatile("s_waitcnt lgkmcnt(0)" ::: "memory");

    if (cl < NCAND) {
        int rank = 0;
        #pragma unroll 4
        for (int o = 0; o < NCAND; ++o) {
            double so = rs[(wv * 2 + t) * NCAND + o];
            int    jo = candj[(wv * 2 + t) * NCAND + o];
            rank += (so < s || (so == s && jo < myj)) ? 1 : 0;
        }
        if (rank < K_SEL) {
            const int pwin = COMP * 64 + plbase + t;
            const int gp   = win * 256 + pwin;
            feat[gp * 48 + rank] = (float)(1.0 - s * 0.03125);
            float dh = (float)((pwin >> 4) - (myj >> 4)) * (1.0f / 15.0f);
            float dw = (float)((pwin & 15) - (myj & 15)) * (1.0f / 15.0f);
            reinterpret_cast<float2*>(feat)[gp * 24 + 8 + rank] = make_float2(dh, dw);
        }
    }
}

__global__ __launch_bounds__(1024) void simtopk_kernel(
    const float* __restrict__ x,    // (64, 256, 32) fp32
    float* __restrict__ feat,       // (16384, 48)
    const float* __restrict__ s0w, const float* __restrict__ s1w,
    const float* __restrict__ sow, const float* __restrict__ o0w,
    const float* __restrict__ o1w, const float* __restrict__ oow,
    short* __restrict__ wpack)
{
    __shared__ __align__(16) float xsT[8192];          // 32 KB
    __shared__ int    candj[16 * 2 * NCAND];
    __shared__ double rs[16 * 2 * NCAND];

    const int tid = threadIdx.x;

    if (blockIdx.x >= 512) {                            // pack tail blocks
        pack_body((blockIdx.x - 512) * 1024 + tid,
                  s0w, s1w, sow, o0w, o1w, oow, wpack);
        return;
    }

    const int win = blockIdx.x >> 3;
    const int grp = blockIdx.x & 7;

    switch (grp >> 1) {                                 // comp is compile-time
        case 0: simtopk_body<0>(x, feat, xsT, candj, rs, win, grp, tid); break;
        case 1: simtopk_body<1>(x, feat, xsT, candj, rs, win, grp, tid); break;
        case 2: simtopk_body<2>(x, feat, xsT, candj, rs, win, grp, tid); break;
        default: simtopk_body<3>(x, feat, xsT, candj, rs, win, grp, tid); break;
    }
}

// ---------------------------------------------------------------------------
// Kernel B (R14-proven, unchanged): 64 px/block, grid 256, 8 waves; wave owns
// one n-tile x M_rep=4 (2 for N=64) M-tiles -> weight set read once per block.
// ---------------------------------------------------------------------------
template<int K_STEPS, int N, bool RELU, bool TO_GLOBAL>
__device__ __forceinline__ void bf16_layer64(
    const short* hiIn, const short* loIn, short* hiOut, short* loOut,
    float* gout, int pbase, const short* __restrict__ wpack, int woff, int sz,
    const float* __restrict__ bias, int wv, int lane, int out_col_off)
{
    const int nt   = (N == 128) ? wv : (wv & 3);
    const int mt0  = (N == 128) ? 0  : ((wv >> 2) * 2);
    const int MREP = (N == 128) ? 4  : 2;
    const int kb   = lane >> 4;
    const int n    = nt * 16 + (lane & 15);

    f32x4 acc[4];
    #pragma unroll
    for (int m = 0; m < 4; ++m) acc[m] = (f32x4){0.f, 0.f, 0.f, 0.f};

    #pragma unroll
    for (int ks = 0; ks < K_STEPS; ++ks) {
        const int wi = woff + ((ks * N + n) * 4 + kb) * 8;
        short8 whi = *(const short8*)(wpack + wi);
        short8 wlo = *(const short8*)(wpack + wi + sz);
        const int g = ks * 4 + kb;
        #pragma unroll
        for (int m = 0; m < MREP; ++m) {
            const int m_a = (mt0 + m) * 16 + (lane & 15);
            const int off = m_a * 256 + ((g ^ (m_a & 7)) << 4);
            short8 ahi = *(const short8*)((const char*)hiIn + off);
            short8 alo = *(const short8*)((const char*)loIn + off);
            acc[m] = __builtin_amdgcn_mfma_f32_16x16x32_bf16(ahi, whi, acc[m], 0, 0, 0);
            acc[m] = __builtin_amdgcn_mfma_f32_16x16x32_bf16(ahi, wlo, acc[m], 0, 0, 0);
            acc[m] = __builtin_amdgcn_mfma_f32_16x16x32_bf16(alo, whi, acc[m], 0, 0, 0);
        }
    }

    const float bv = bias[n];
    #pragma unroll
    for (int m = 0; m < MREP; ++m) {
        #pragma unroll
        for (int r = 0; r < 4; ++r) {
            float v = acc[m][r] + bv;
            if (RELU) v = fmaxf(v, 0.0f);
            const int pw = (mt0 + m) * 16 + (lane >> 4) * 4 + r;
            if (TO_GLOBAL) {
                gout[(size_t)(pbase + pw) * 64 + n] = v;
            } else {
                const int w   = out_col_off + n;
                const int off = pw * 256 + ((((w >> 3) ^ (pw & 7))) << 4) + (w & 7) * 2;
                short h = f2bf_bits(v);
                short l = f2bf_bits(v - bf2f_bits(h));
                *(short*)((char*)hiOut + off) = h;
                *(short*)((char*)loOut + off) = l;
            }
        }
    }
}

__global__ __launch_bounds__(512) void ffn_kernel(
    const float* __restrict__ x,     // (16384, 32)
    const float* __restrict__ feat,  // (16384, 48)
    const short* __restrict__ wpack,
    const float* __restrict__ s0b, const float* __restrict__ s1b,
    const float* __restrict__ sob, const float* __restrict__ o0b,
    const float* __restrict__ o1b, const float* __restrict__ oob,
    float* __restrict__ out)         // (16384, 64)
{
    __shared__ __align__(16) short hiA[64 * 128];   // 16 KB each
    __shared__ __align__(16) short loA[64 * 128];
    __shared__ __align__(16) short hiB[64 * 128];
    __shared__ __align__(16) short loB[64 * 128];

    const int tid   = threadIdx.x;
    const int lane  = tid & 63;
    const int wv    = tid >> 6;                   // 0..7
    const int pbase = blockIdx.x * 64;

    // ---- stage feat (cols 0..47, split) + zero cols 48..63 into planes A ----
    #pragma unroll
    for (int rr = 0; rr < 2; ++rr) {
        int u = tid + rr * 512;
        if (u < 768) {
            int p = u / 12, c4 = u - p * 12;
            f32x4 v = ((const f32x4*)feat)[(size_t)(pbase + p) * 12 + c4];
            short4v h4, l4;
            #pragma unroll
            for (int j = 0; j < 4; ++j) {
                short h = f2bf_bits(v[j]);
                h4[j] = h;
                l4[j] = f2bf_bits(v[j] - bf2f_bits(h));
            }
            int off = p * 256 + ((((c4 >> 1) ^ (p & 7))) << 4) + (c4 & 1) * 8;
            *(short4v*)((char*)hiA + off) = h4;
            *(short4v*)((char*)loA + off) = l4;
        }
    }
    if (tid < 256) {
        int p = tid >> 2, sel = tid & 3;          // 64 rows x {g6,g7} x {hi,lo}
        int g = 6 + (sel & 1);
        int off = p * 256 + ((g ^ (p & 7)) << 4);
        short8 z = (short8){0,0,0,0,0,0,0,0};
        if (sel >> 1) *(short8*)((char*)loA + off) = z;
        else          *(short8*)((char*)hiA + off) = z;
    }
    __syncthreads();

    // L1: 48(+pad) -> 128 relu   (A -> B)
    bf16_layer64<2, 128, true, false>(hiA, loA, hiB, loB, nullptr, pbase,
                                      wpack, 0, 8192, s0b, wv, lane, 0);
    __syncthreads();
    // L2: 128 -> 128 relu  (B -> A)
    bf16_layer64<4, 128, true, false>(hiB, loB, hiA, loA, nullptr, pbase,
                                      wpack, 16384, 16384, s1b, wv, lane, 0);
    __syncthreads();
    // L3: 128 -> 64 (sf) into B cols 32..95 ; stage x into B cols 0..31
    {
        int p = tid >> 3, c4 = tid & 7;           // 512 threads = 64 rows x 8
        f32x4 v = ((const f32x4*)x)[(size_t)(pbase + p) * 8 + c4];
        short4v h4, l4;
        #pragma unroll
        for (int j = 0; j < 4; ++j) {
            short h = f2bf_bits(v[j]);
            h4[j] = h;
            l4[j] = f2bf_bits(v[j] - bf2f_bits(h));
        }
        int off = p * 256 + ((((c4 >> 1) ^ (p & 7))) << 4) + (c4 & 1) * 8;
        *(short4v*)((char*)hiB + off) = h4;
        *(short4v*)((char*)loB + off) = l4;
    }
    bf16_layer64<4, 64, false, false>(hiA, loA, hiB, loB, nullptr, pbase,
                                      wpack, 49152, 8192, sob, wv, lane, 32);
    __syncthreads();
    // L4: 96 -> 128 relu  (B -> A)
    bf16_layer64<3, 128, true, false>(hiB, loB, hiA, loA, nullptr, pbase,
                                      wpack, 65536, 12288, o0b, wv, lane, 0);
    __syncthreads();
    // L5: 128 -> 128 relu  (A -> B)
    bf16_layer64<4, 128, true, false>(hiA, loA, hiB, loB, nullptr, pbase,
                                      wpack, 90112, 16384, o1b, wv, lane, 0);
    __syncthreads();
    // L6: 128 -> 64 (+bias) -> out
    bf16_layer64<4, 64, false, true>(hiB, loB, nullptr, nullptr, out, pbase,
                                     wpack, 122880, 8192, oob, wv, lane, 0);
}

extern "C" void kernel_launch(void* const* d_in, const int* in_sizes, int n_in,
                              void* d_out, int out_size, void* d_ws, size_t ws_size,
                              hipStream_t stream) {
    const float* x    = (const float*)d_in[0];
    const float* s0w  = (const float*)d_in[1];
    const float* s0b  = (const float*)d_in[2];
    const float* s1w  = (const float*)d_in[3];
    const float* s1b  = (const float*)d_in[4];
    const float* sow  = (const float*)d_in[5];
    const float* sob  = (const float*)d_in[6];
    const float* o0w  = (const float*)d_in[7];
    const float* o0b  = (const float*)d_in[8];
    const float* o1w  = (const float*)d_in[9];
    const float* o1b  = (const float*)d_in[10];
    const float* oow  = (const float*)d_in[11];
    const float* oob  = (const float*)d_in[12];

    short* wpack = (short*)d_ws;                      // 278528 B
    float* feat  = (float*)((char*)d_ws + 524288);    // 16384*48 fp32
    float* out   = (float*)d_out;

    simtopk_kernel<<<580, 1024, 0, stream>>>(x, feat,
                                             s0w, s1w, sow, o0w, o1w, oow, wpack);
    ffn_kernel<<<256, 512, 0, stream>>>(x, feat, wpack,
                                        s0b, s1b, sob, o0b, o1b, oob,
                                        out);
}

// Round 22
// 47.246 us; speedup vs baseline: 1.0356x; 1.0036x over previous
//
#include <hip/hip_runtime.h>
#include <hip/hip_bf16.h>

#define K_SEL 16
#define NCAND 20

typedef __attribute__((ext_vector_type(8))) short short8;
typedef __attribute__((ext_vector_type(4))) short short4v;
typedef __attribute__((ext_vector_type(4))) float f32x4;

__device__ __forceinline__ short f2bf_bits(float v) {
    union { __hip_bfloat16 b; short s; } u;
    u.b = __float2bfloat16(v);                    // RNE HW convert
    return u.s;
}
__device__ __forceinline__ float bf2f_bits(short h) {
    return __uint_as_float(((unsigned)(unsigned short)h) << 16);
}
__device__ __forceinline__ float readlane_f(float v, int l) {
    return __int_as_float(__builtin_amdgcn_readlane(__float_as_int(v), l));
}

// ---------------------------------------------------------------------------
// pack body (tail blocks of simtopk): weights -> split-bf16 hi/lo planes,
// B-fragment order idx = ((ks*N + n)*4 + kb)*8 + i <-> W[ks*32+kb*8+i][n].
// __noinline__ so the hot simtopk path's regalloc is not perturbed (R9 lesson).
// ---------------------------------------------------------------------------
__device__ __noinline__ void pack_body(
    int t,
    const float* __restrict__ s0w, const float* __restrict__ s1w,
    const float* __restrict__ sow, const float* __restrict__ o0w,
    const float* __restrict__ o1w, const float* __restrict__ oow,
    short* __restrict__ wpack)
{
    if (t >= 69632) return;
    int l, base;
    if      (t <  8192) { l = 0; base = 0;     }
    else if (t < 24576) { l = 1; base = 8192;  }
    else if (t < 32768) { l = 2; base = 24576; }
    else if (t < 45056) { l = 3; base = 32768; }
    else if (t < 61440) { l = 4; base = 45056; }
    else                { l = 5; base = 61440; }

    const float* W = (l == 0) ? s0w : (l == 1) ? s1w : (l == 2) ? sow
                   : (l == 3) ? o0w : (l == 4) ? o1w : oow;
    int N    = (l == 2 || l == 5) ? 64 : 128;
    int Kr   = (l == 0) ? 48 : (l == 3) ? 96 : 128;
    int woff = (l == 0) ? 0 : (l == 1) ? 16384 : (l == 2) ? 49152
             : (l == 3) ? 65536 : (l == 4) ? 90112 : 122880;
    int sz   = (l == 2 || l == 5) ? 8192 : (l == 3) ? 12288 : (l == 0) ? 8192 : 16384;

    int e = t - base;
    int i = e & 7, kb = (e >> 3) & 3, rem = e >> 5;
    int n = rem % N, ks = rem / N;
    int k = ks * 32 + kb * 8 + i;
    float v = (k < Kr) ? W[k * N + n] : 0.0f;
    short hi = f2bf_bits(v);
    float lo = v - bf2f_bits(hi);
    wpack[woff + e]      = hi;
    wpack[woff + sz + e] = f2bf_bits(lo);
}

// ---------------------------------------------------------------------------
// Kernel A (R19-measured-best, byte-exact): 2 px/wave distances (readlane of
// the candidate vector), all-thread staging (each thread: 2 f4 loads + 4 b64
// writes -> bit-identical LDS image, no idle waves), radix top-20, fp64
// re-rank from global rows, rank via LDS rs[].
// grid 512(+68 pack tail) = 64 win x 8 groups of 32 px; block 1024 = 16 waves.
// ---------------------------------------------------------------------------
template<int COMP>
__device__ __forceinline__ void simtopk_body(
    const float* __restrict__ x, float* __restrict__ feat,
    float* xsT, int* candj, double* rs, int win, int grp, int tid)
{
    const int lane = tid & 63;
    const int wv   = tid >> 6;

    // ---- stage transposed window: ALL threads; 2 f4 loads + 4 b64 writes ----
    {
        const int half = tid >> 9;                 // 0: quadrants 0,1; 1: 2,3
        const int t2   = tid & 511;
        const int c4   = t2 & 7, jb = t2 >> 3;     // jb in [0,64)
        const float4* gx = reinterpret_cast<const float4*>(x + (size_t)win * 8192);
        float4 va = gx[jb * 8 + c4 + (half ? 1024 : 0)];
        float4 vb = gx[jb * 8 + c4 + (half ? 1536 : 512)];
        const int gsw = jb ^ c4;
        char* bp = (char*)xsT + (size_t)half * 8;
        #pragma unroll
        for (int k = 0; k < 4; ++k) {
            float2 h2 = make_float2((&va.x)[k], (&vb.x)[k]);
            *(float2*)(bp + ((4 * c4 + k) * 64 + gsw) * 16) = h2;
        }
    }
    __syncthreads();

    const int plbase = (grp & 1) * 32 + wv * 2;

    const f32x4* xsT4c = reinterpret_cast<const f32x4*>(xsT);
    float acc0[4] = {0.f, 0.f, 0.f, 0.f};
    float acc1[4] = {0.f, 0.f, 0.f, 0.f};
    #pragma unroll
    for (int c = 0; c < 32; ++c) {
        f32x4 a = xsT4c[c * 64 + (lane ^ ((c >> 2) & 7))];
        float xi0 = readlane_f(a[COMP], plbase);
        float xi1 = readlane_f(a[COMP], plbase + 1);
        #pragma unroll
        for (int q = 0; q < 4; ++q) {
            acc0[q] += fabsf(a[q] - xi0);
            acc1[q] += fabsf(a[q] - xi1);
        }
    }
    unsigned int p0[4], p1[4];
    #pragma unroll
    for (int q = 0; q < 4; ++q) {
        p0[q] = (__float_as_uint(acc0[q]) & 0xFFFFFF00u) | (unsigned)(q * 64 + lane);
        p1[q] = (__float_as_uint(acc1[q]) & 0xFFFFFF00u) | (unsigned)(q * 64 + lane);
    }

    unsigned int T0 = 0, T1 = 0;
    for (int bit = 31; bit >= 0; --bit) {
        unsigned int c0 = T0 | (1u << bit), c1 = T1 | (1u << bit);
        int n0 = __popcll(__ballot(p0[0] < c0)) + __popcll(__ballot(p0[1] < c0))
               + __popcll(__ballot(p0[2] < c0)) + __popcll(__ballot(p0[3] < c0));
        int n1 = __popcll(__ballot(p1[0] < c1)) + __popcll(__ballot(p1[1] < c1))
               + __popcll(__ballot(p1[2] < c1)) + __popcll(__ballot(p1[3] < c1));
        if (n0 < NCAND) T0 = c0;
        if (n1 < NCAND) T1 = c1;
    }

    const unsigned long long lt = (1ull << lane) - 1ull;
    int base0 = 0, base1 = 0;
    #pragma unroll
    for (int q = 0; q < 4; ++q) {
        bool s0 = (p0[q] <= T0);
        unsigned long long m0 = __ballot(s0);
        if (s0) candj[(wv * 2 + 0) * NCAND + base0 + __popcll(m0 & lt)] = q * 64 + lane;
        base0 += __popcll(m0);
        bool s1 = (p1[q] <= T1);
        unsigned long long m1 = __ballot(s1);
        if (s1) candj[(wv * 2 + 1) * NCAND + base1 + __popcll(m1 & lt)] = q * 64 + lane;
        base1 += __popcll(m1);
    }
    asm volatile("s_waitcnt lgkmcnt(0)" ::: "memory");

    const int t  = lane >> 5;
    const int cl = lane & 31;
    double s = 0.0;
    int myj = -1;
    if (cl < NCAND) {
        myj = candj[(wv * 2 + t) * NCAND + cl];
        const int pwin = COMP * 64 + plbase + t;          // FULL window-pixel idx
        const float4* xj = reinterpret_cast<const float4*>(x + (size_t)win * 8192 + (size_t)myj * 32);
        const float4* xp = reinterpret_cast<const float4*>(x + (size_t)win * 8192 + (size_t)pwin * 32);
        #pragma unroll
        for (int c4 = 0; c4 < 8; ++c4) {
            float4 b = xj[c4];
            float4 a = xp[c4];
            s += fabs((double)a.x - (double)b.x);
            s += fabs((double)a.y - (double)b.y);
            s += fabs((double)a.z - (double)b.z);
            s += fabs((double)a.w - (double)b.w);
        }
        rs[(wv * 2 + t) * NCAND + cl] = s;
    }
    asm volatile("s_waitcnt lgkmcnt(0)" ::: "memory");

    if (cl < NCAND) {
        int rank = 0;
        #pragma unroll 4
        for (int o = 0; o < NCAND; ++o) {
            double so = rs[(wv * 2 + t) * NCAND + o];
            int    jo = candj[(wv * 2 + t) * NCAND + o];
            rank += (so < s || (so == s && jo < myj)) ? 1 : 0;
        }
        if (rank < K_SEL) {
            const int pwin = COMP * 64 + plbase + t;
            const int gp   = win * 256 + pwin;
            feat[gp * 48 + rank] = (float)(1.0 - s * 0.03125);
            float dh = (float)((pwin >> 4) - (myj >> 4)) * (1.0f / 15.0f);
            float dw = (float)((pwin & 15) - (myj & 15)) * (1.0f / 15.0f);
            reinterpret_cast<float2*>(feat)[gp * 24 + 8 + rank] = make_float2(dh, dw);
        }
    }
}

__global__ __launch_bounds__(1024) void simtopk_kernel(
    const float* __restrict__ x,    // (64, 256, 32) fp32
    float* __restrict__ feat,       // (16384, 48)
    const float* __restrict__ s0w, const float* __restrict__ s1w,
    const float* __restrict__ sow, const float* __restrict__ o0w,
    const float* __restrict__ o1w, const float* __restrict__ oow,
    short* __restrict__ wpack)
{
    __shared__ __align__(16) float xsT[8192];          // 32 KB
    __shared__ int    candj[16 * 2 * NCAND];
    __shared__ double rs[16 * 2 * NCAND];

    const int tid = threadIdx.x;

    if (blockIdx.x >= 512) {                            // pack tail blocks
        pack_body((blockIdx.x - 512) * 1024 + tid,
                  s0w, s1w, sow, o0w, o1w, oow, wpack);
        return;
    }

    const int win = blockIdx.x >> 3;
    const int grp = blockIdx.x & 7;

    switch (grp >> 1) {                                 // comp is compile-time
        case 0: simtopk_body<0>(x, feat, xsT, candj, rs, win, grp, tid); break;
        case 1: simtopk_body<1>(x, feat, xsT, candj, rs, win, grp, tid); break;
        case 2: simtopk_body<2>(x, feat, xsT, candj, rs, win, grp, tid); break;
        default: simtopk_body<3>(x, feat, xsT, candj, rs, win, grp, tid); break;
    }
}

// ---------------------------------------------------------------------------
// Kernel B (R14-proven, unchanged): 64 px/block, grid 256, 8 waves; wave owns
// one n-tile x M_rep=4 (2 for N=64) M-tiles -> weight set read once per block.
// ---------------------------------------------------------------------------
template<int K_STEPS, int N, bool RELU, bool TO_GLOBAL>
__device__ __forceinline__ void bf16_layer64(
    const short* hiIn, const short* loIn, short* hiOut, short* loOut,
    float* gout, int pbase, const short* __restrict__ wpack, int woff, int sz,
    const float* __restrict__ bias, int wv, int lane, int out_col_off)
{
    const int nt   = (N == 128) ? wv : (wv & 3);
    const int mt0  = (N == 128) ? 0  : ((wv >> 2) * 2);
    const int MREP = (N == 128) ? 4  : 2;
    const int kb   = lane >> 4;
    const int n    = nt * 16 + (lane & 15);

    f32x4 acc[4];
    #pragma unroll
    for (int m = 0; m < 4; ++m) acc[m] = (f32x4){0.f, 0.f, 0.f, 0.f};

    #pragma unroll
    for (int ks = 0; ks < K_STEPS; ++ks) {
        const int wi = woff + ((ks * N + n) * 4 + kb) * 8;
        short8 whi = *(const short8*)(wpack + wi);
        short8 wlo = *(const short8*)(wpack + wi + sz);
        const int g = ks * 4 + kb;
        #pragma unroll
        for (int m = 0; m < MREP; ++m) {
            const int m_a = (mt0 + m) * 16 + (lane & 15);
            const int off = m_a * 256 + ((g ^ (m_a & 7)) << 4);
            short8 ahi = *(const short8*)((const char*)hiIn + off);
            short8 alo = *(const short8*)((const char*)loIn + off);
            acc[m] = __builtin_amdgcn_mfma_f32_16x16x32_bf16(ahi, whi, acc[m], 0, 0, 0);
            acc[m] = __builtin_amdgcn_mfma_f32_16x16x32_bf16(ahi, wlo, acc[m], 0, 0, 0);
            acc[m] = __builtin_amdgcn_mfma_f32_16x16x32_bf16(alo, whi, acc[m], 0, 0, 0);
        }
    }

    const float bv = bias[n];
    #pragma unroll
    for (int m = 0; m < MREP; ++m) {
        #pragma unroll
        for (int r = 0; r < 4; ++r) {
            float v = acc[m][r] + bv;
            if (RELU) v = fmaxf(v, 0.0f);
            const int pw = (mt0 + m) * 16 + (lane >> 4) * 4 + r;
            if (TO_GLOBAL) {
                gout[(size_t)(pbase + pw) * 64 + n] = v;
            } else {
                const int w   = out_col_off + n;
                const int off = pw * 256 + ((((w >> 3) ^ (pw & 7))) << 4) + (w & 7) * 2;
                short h = f2bf_bits(v);
                short l = f2bf_bits(v - bf2f_bits(h));
                *(short*)((char*)hiOut + off) = h;
                *(short*)((char*)loOut + off) = l;
            }
        }
    }
}

__global__ __launch_bounds__(512) void ffn_kernel(
    const float* __restrict__ x,     // (16384, 32)
    const float* __restrict__ feat,  // (16384, 48)
    const short* __restrict__ wpack,
    const float* __restrict__ s0b, const float* __restrict__ s1b,
    const float* __restrict__ sob, const float* __restrict__ o0b,
    const float* __restrict__ o1b, const float* __restrict__ oob,
    float* __restrict__ out)         // (16384, 64)
{
    __shared__ __align__(16) short hiA[64 * 128];   // 16 KB each
    __shared__ __align__(16) short loA[64 * 128];
    __shared__ __align__(16) short hiB[64 * 128];
    __shared__ __align__(16) short loB[64 * 128];

    const int tid   = threadIdx.x;
    const int lane  = tid & 63;
    const int wv    = tid >> 6;                   // 0..7
    const int pbase = blockIdx.x * 64;

    // ---- stage feat (cols 0..47, split) + zero cols 48..63 into planes A ----
    #pragma unroll
    for (int rr = 0; rr < 2; ++rr) {
        int u = tid + rr * 512;
        if (u < 768) {
            int p = u / 12, c4 = u - p * 12;
            f32x4 v = ((const f32x4*)feat)[(size_t)(pbase + p) * 12 + c4];
            short4v h4, l4;
            #pragma unroll
            for (int j = 0; j < 4; ++j) {
                short h = f2bf_bits(v[j]);
                h4[j] = h;
                l4[j] = f2bf_bits(v[j] - bf2f_bits(h));
            }
            int off = p * 256 + ((((c4 >> 1) ^ (p & 7))) << 4) + (c4 & 1) * 8;
            *(short4v*)((char*)hiA + off) = h4;
            *(short4v*)((char*)loA + off) = l4;
        }
    }
    if (tid < 256) {
        int p = tid >> 2, sel = tid & 3;          // 64 rows x {g6,g7} x {hi,lo}
        int g = 6 + (sel & 1);
        int off = p * 256 + ((g ^ (p & 7)) << 4);
        short8 z = (short8){0,0,0,0,0,0,0,0};
        if (sel >> 1) *(short8*)((char*)loA + off) = z;
        else          *(short8*)((char*)hiA + off) = z;
    }
    __syncthreads();

    // L1: 48(+pad) -> 128 relu   (A -> B)
    bf16_layer64<2, 128, true, false>(hiA, loA, hiB, loB, nullptr, pbase,
                                      wpack, 0, 8192, s0b, wv, lane, 0);
    __syncthreads();
    // L2: 128 -> 128 relu  (B -> A)
    bf16_layer64<4, 128, true, false>(hiB, loB, hiA, loA, nullptr, pbase,
                                      wpack, 16384, 16384, s1b, wv, lane, 0);
    __syncthreads();
    // L3: 128 -> 64 (sf) into B cols 32..95 ; stage x into B cols 0..31
    {
        int p = tid >> 3, c4 = tid & 7;           // 512 threads = 64 rows x 8
        f32x4 v = ((const f32x4*)x)[(size_t)(pbase + p) * 8 + c4];
        short4v h4, l4;
        #pragma unroll
        for (int j = 0; j < 4; ++j) {
            short h = f2bf_bits(v[j]);
            h4[j] = h;
            l4[j] = f2bf_bits(v[j] - bf2f_bits(h));
        }
        int off = p * 256 + ((((c4 >> 1) ^ (p & 7))) << 4) + (c4 & 1) * 8;
        *(short4v*)((char*)hiB + off) = h4;
        *(short4v*)((char*)loB + off) = l4;
    }
    bf16_layer64<4, 64, false, false>(hiA, loA, hiB, loB, nullptr, pbase,
                                      wpack, 49152, 8192, sob, wv, lane, 32);
    __syncthreads();
    // L4: 96 -> 128 relu  (B -> A)
    bf16_layer64<3, 128, true, false>(hiB, loB, hiA, loA, nullptr, pbase,
                                      wpack, 65536, 12288, o0b, wv, lane, 0);
    __syncthreads();
    // L5: 128 -> 128 relu  (A -> B)
    bf16_layer64<4, 128, true, false>(hiA, loA, hiB, loB, nullptr, pbase,
                                      wpack, 90112, 16384, o1b, wv, lane, 0);
    __syncthreads();
    // L6: 128 -> 64 (+bias) -> out
    bf16_layer64<4, 64, false, true>(hiB, loB, nullptr, nullptr, out, pbase,
                                     wpack, 122880, 8192, oob, wv, lane, 0);
}

extern "C" void kernel_launch(void* const* d_in, const int* in_sizes, int n_in,
                              void* d_out, int out_size, void* d_ws, size_t ws_size,
                              hipStream_t stream) {
    const float* x    = (const float*)d_in[0];
    const float* s0w  = (const float*)d_in[1];
    const float* s0b  = (const float*)d_in[2];
    const float* s1w  = (const float*)d_in[3];
    const float* s1b  = (const float*)d_in[4];
    const float* sow  = (const float*)d_in[5];
    const float* sob  = (const float*)d_in[6];
    const float* o0w  = (const float*)d_in[7];
    const float* o0b  = (const float*)d_in[8];
    const float* o1w  = (const float*)d_in[9];
    const float* o1b  = (const float*)d_in[10];
    const float* oow  = (const float*)d_in[11];
    const float* oob  = (const float*)d_in[12];

    short* wpack = (short*)d_ws;                      // 278528 B
    float* feat  = (float*)((char*)d_ws + 524288);    // 16384*48 fp32
    float* out   = (float*)d_out;

    simtopk_kernel<<<580, 1024, 0, stream>>>(x, feat,
                                             s0w, s1w, sow, o0w, o1w, oow, wpack);
    ffn_kernel<<<256, 512, 0, stream>>>(x, feat, wpack,
                                        s0b, s1b, sob, o0b, o1b, oob,
                                        out);
}